// Round 5
// baseline (5698.803 us; speedup 1.0000x reference)
//
#include <hip/hip_runtime.h>
#include <cstdint>
#include <cstddef>

#define N_TOK 8192
#define DIM   2048
#define VOC   32000
#define BT    128            // token rows per block
#define BV    128            // vocab cols per block
#define NVT   (VOC / BV)     // 250 vocab tiles
#define NNT   (N_TOK / BT)   // 64 token tiles
#define KSTEPS (DIM / 64)    // 32 K-steps of 64 fp8 elems (one 32x32x64 MFMA each)
#define IGNORE_IDX (-100)

// prescale inputs by 2^6 at cast; both MX scales = 2^-6 (e8m0 byte 121)
// => dequant (64a * 2^-6)(64b * 2^-6) = a*b exactly.  (verified r2-r4, absmax 0.0)
#define PRESCALE 64.0f
#define SCALE_E8M0 0x79797979

typedef __attribute__((ext_vector_type(4)))  int   i32x4;
typedef __attribute__((ext_vector_type(8)))  int   i32x8;
typedef __attribute__((ext_vector_type(16))) float f32x16;

// Fragment-tiled fp8 layout: for 32-row-block R, K-step t (64 bytes of K),
// lane l (l31 = l&31 -> row, half = l>>5 -> K-half of 32B):
//   offset = (R*32 + t)*2048 + (half*32 + l31)*32
// A wave frag load = 64 lanes x 32 B = 2 KB fully contiguous.
__device__ __forceinline__ size_t frag_off(int row, int k32) {
    // inverse mapping used by the cast kernel: k32 = 32-byte K-chunk index
    return ((size_t)(row >> 5) * 32 + (k32 >> 1)) * 2048
         + (size_t)(((k32 & 1) << 5) + (row & 31)) * 32;
}

__device__ __forceinline__ void cast32(const float* __restrict__ src, unsigned char* __restrict__ dst) {
    int w[8];
#pragma unroll
    for (int j = 0; j < 4; ++j) {
        float4 x = ((const float4*)src)[2 * j];
        float4 y = ((const float4*)src)[2 * j + 1];
        int lo = __builtin_amdgcn_cvt_pk_fp8_f32(x.x * PRESCALE, x.y * PRESCALE, 0, false);
        lo     = __builtin_amdgcn_cvt_pk_fp8_f32(x.z * PRESCALE, x.w * PRESCALE, lo, true);
        int hi = __builtin_amdgcn_cvt_pk_fp8_f32(y.x * PRESCALE, y.y * PRESCALE, 0, false);
        hi     = __builtin_amdgcn_cvt_pk_fp8_f32(y.z * PRESCALE, y.w * PRESCALE, hi, true);
        w[2 * j] = lo; w[2 * j + 1] = hi;
    }
    ((int4*)dst)[0] = make_int4(w[0], w[1], w[2], w[3]);
    ((int4*)dst)[1] = make_int4(w[4], w[5], w[6], w[7]);
}

// ---------------------------------------------------------------------------
// Kernel 1: cast H and W to fp8 e4m3 in MFMA-fragment-tiled layout; zero out.
// One task = 32 consecutive K elems of one row (read 128 B fp32, write 32 B).
// Wave covers one row's 64 k-chunks -> reads 8 KB contiguous.
// ---------------------------------------------------------------------------
__global__ void cast_zero_kernel(const float* __restrict__ H, const float* __restrict__ W,
                                 unsigned char* __restrict__ Ht, unsigned char* __restrict__ Wt,
                                 float* __restrict__ out)
{
    if (blockIdx.x == 0 && threadIdx.x == 0) out[0] = 0.0f;
    const size_t nhT = (size_t)N_TOK * 64;
    const size_t nwT = (size_t)VOC * 64;
    size_t t = (size_t)blockIdx.x * blockDim.x + threadIdx.x;
    size_t stride = (size_t)gridDim.x * blockDim.x;
    for (size_t id = t; id < nhT; id += stride) {
        int row = (int)(id >> 6), k32 = (int)(id & 63);
        cast32(H + (size_t)row * DIM + (size_t)k32 * 32, Ht + frag_off(row, k32));
    }
    for (size_t id = t; id < nwT; id += stride) {
        int row = (int)(id >> 6), k32 = (int)(id & 63);
        cast32(W + (size_t)row * DIM + (size_t)k32 * 32, Wt + frag_off(row, k32));
    }
}

// ---------------------------------------------------------------------------
// Kernel 2: flatmm-style MX-fp8 GEMM, 32x32x64 scaled MFMA, NO LDS staging,
// NO K-loop barriers. Operands stream straight from L2/L3 (fragment-tiled
// layout => each frag is one coalesced 2-KB wave load). Register prefetch of
// step t+1 overlaps the 4 MFMAs of step t; compiler emits fine-grained
// vmcnt(N) waits (AITER pattern) since nothing forces a drain.
// ---------------------------------------------------------------------------
__global__ __launch_bounds__(256, 3)
void lmhead_gemm(const unsigned char* __restrict__ Ht,
                 const unsigned char* __restrict__ Wt,
                 const int* __restrict__ labels,
                 float* __restrict__ partMax,
                 float* __restrict__ partSum,
                 float* __restrict__ tgt)
{
    __shared__ float pm[2][BT];
    __shared__ float ps[2][BT];
    __shared__ int   ltgt[BT];

    // supergroup-of-8 swizzle for L2 locality
    int b = blockIdx.x;
    const int SG = 8;
    int group = b / (SG * NVT);
    int rem   = b % (SG * NVT);
    int vt    = rem / SG;
    int nt    = group * SG + (rem % SG);

    const int tid  = threadIdx.x;
    const int wave = tid >> 6;
    const int lane = tid & 63;
    const int wm   = wave >> 1;                // wave row (0..1) -> 64 token rows
    const int wn   = wave & 1;                 // wave col (0..1) -> 64 vocab cols
    const int l31  = lane & 31;
    const int half = lane >> 5;

    const int rowBase = nt * BT;
    const int colBase = vt * BV;

    if (tid < BT) {
        int lb = labels[rowBase + tid];
        int lc = lb - colBase;
        ltgt[tid] = (lc >= 0 && lc < BV) ? lc : -1;
    }

    f32x16 acc[2][2];
#pragma unroll
    for (int i = 0; i < 2; ++i)
#pragma unroll
        for (int j = 0; j < 2; ++j)
            acc[i][j] = (f32x16){0.f,0.f,0.f,0.f,0.f,0.f,0.f,0.f,0.f,0.f,0.f,0.f,0.f,0.f,0.f,0.f};

    // fragment stream base: 32-row block index; one (R,t) frag = 2048 B
    const int R0 = nt * 4 + wm * 2;            // A blocks R0, R0+1
    const int C0 = vt * 4 + wn * 2;            // B blocks C0, C0+1
    const unsigned char* aP = Ht + (size_t)R0 * (32 * 2048) + (size_t)lane * 32;
    const unsigned char* bP = Wt + (size_t)C0 * (32 * 2048) + (size_t)lane * 32;

    i32x8 a0 = *(const i32x8*)(aP);
    i32x8 a1 = *(const i32x8*)(aP + 32 * 2048);
    i32x8 b0 = *(const i32x8*)(bP);
    i32x8 b1 = *(const i32x8*)(bP + 32 * 2048);

    for (int t = 0; t < KSTEPS; ++t) {
        const size_t tn = (size_t)((t + 1) & (KSTEPS - 1)) * 2048;
        i32x8 na0 = *(const i32x8*)(aP + tn);
        i32x8 na1 = *(const i32x8*)(aP + 32 * 2048 + tn);
        i32x8 nb0 = *(const i32x8*)(bP + tn);
        i32x8 nb1 = *(const i32x8*)(bP + 32 * 2048 + tn);
        acc[0][0] = __builtin_amdgcn_mfma_scale_f32_32x32x64_f8f6f4(
            a0, b0, acc[0][0], 0, 0, 0, SCALE_E8M0, 0, SCALE_E8M0);
        acc[0][1] = __builtin_amdgcn_mfma_scale_f32_32x32x64_f8f6f4(
            a0, b1, acc[0][1], 0, 0, 0, SCALE_E8M0, 0, SCALE_E8M0);
        acc[1][0] = __builtin_amdgcn_mfma_scale_f32_32x32x64_f8f6f4(
            a1, b0, acc[1][0], 0, 0, 0, SCALE_E8M0, 0, SCALE_E8M0);
        acc[1][1] = __builtin_amdgcn_mfma_scale_f32_32x32x64_f8f6f4(
            a1, b1, acc[1][1], 0, 0, 0, SCALE_E8M0, 0, SCALE_E8M0);
        a0 = na0; a1 = na1; b0 = nb0; b1 = nb1;
    }

    __syncthreads();   // ltgt visibility for the epilogue

    // ---- fused epilogue: per-row max & sum(exp) over this block's 128 cols ----
    // 32x32 C/D layout: col = lane&31, row = (reg&3) + 8*(reg>>2) + 4*(lane>>5)
#pragma unroll
    for (int i = 0; i < 2; ++i) {
#pragma unroll
        for (int r = 0; r < 16; ++r) {
            float v0 = acc[i][0][r], v1 = acc[i][1][r];
            float mx = fmaxf(v0, v1);
            mx = fmaxf(mx, __shfl_xor(mx, 1));
            mx = fmaxf(mx, __shfl_xor(mx, 2));
            mx = fmaxf(mx, __shfl_xor(mx, 4));
            mx = fmaxf(mx, __shfl_xor(mx, 8));
            mx = fmaxf(mx, __shfl_xor(mx, 16));
            float s = __expf(v0 - mx) + __expf(v1 - mx);
            s += __shfl_xor(s, 1);
            s += __shfl_xor(s, 2);
            s += __shfl_xor(s, 4);
            s += __shfl_xor(s, 8);
            s += __shfl_xor(s, 16);
            int localRow = wm * 64 + i * 32 + (r & 3) + 8 * (r >> 2) + 4 * half;
            if (l31 == 0) { pm[wn][localRow] = mx; ps[wn][localRow] = s; }
            int tc = ltgt[localRow];
            if (tc >= 0) {
#pragma unroll
                for (int j = 0; j < 2; ++j) {
                    if (wn * 64 + j * 32 + l31 == tc)
                        tgt[rowBase + localRow] = acc[i][j][r];
                }
            }
        }
    }
    __syncthreads();

    if (tid < BT) {
        float m0 = pm[0][tid], m1 = pm[1][tid];
        float M = fmaxf(m0, m1);
        float S = ps[0][tid] * __expf(m0 - M) + ps[1][tid] * __expf(m1 - M);
        size_t o = (size_t)vt * N_TOK + rowBase + tid;
        partMax[o] = M;
        partSum[o] = S;
    }
}

// ---------------------------------------------------------------------------
// Kernel 3: per-row online logsumexp over 250 tile-partials, NLL, global sum.
// ---------------------------------------------------------------------------
__global__ void reduce_kernel(const float* __restrict__ partMax,
                              const float* __restrict__ partSum,
                              const float* __restrict__ tgt,
                              const int* __restrict__ labels,
                              float* __restrict__ out)
{
    __shared__ float red[4];
    const int tid = threadIdx.x;
    const int n = blockIdx.x * blockDim.x + tid;

    float M = -1e30f, S = 0.f;
    for (int t = 0; t < NVT; ++t) {
        float m = partMax[(size_t)t * N_TOK + n];  // coalesced
        float s = partSum[(size_t)t * N_TOK + n];
        float nM = fmaxf(M, m);
        S = S * __expf(M - nM) + s * __expf(m - nM);
        M = nM;
    }
    int lb = labels[n];
    float nll = 0.f;
    if (lb != IGNORE_IDX) nll = __logf(S) + M - tgt[n];

    float v = nll;
    v += __shfl_xor(v, 32);
    v += __shfl_xor(v, 16);
    v += __shfl_xor(v, 8);
    v += __shfl_xor(v, 4);
    v += __shfl_xor(v, 2);
    v += __shfl_xor(v, 1);
    if ((tid & 63) == 0) red[tid >> 6] = v;
    __syncthreads();
    if (tid == 0) atomicAdd(out, red[0] + red[1] + red[2] + red[3]);
}

// ---------------------------------------------------------------------------
extern "C" void kernel_launch(void* const* d_in, const int* in_sizes, int n_in,
                              void* d_out, int out_size, void* d_ws, size_t ws_size,
                              hipStream_t stream)
{
    const float* H      = (const float*)d_in[0];   // [8192, 2048] fp32
    const int*   labels = (const int*)d_in[1];     // [8192]
    const float* W      = (const float*)d_in[2];   // [32000, 2048] fp32
    float* out = (float*)d_out;

    char* ws = (char*)d_ws;
    size_t need = (size_t)VOC * DIM + (size_t)N_TOK * DIM
                + 2 * (size_t)NVT * N_TOK * 4 + (size_t)N_TOK * 4;
    if (ws_size < need) return;

    unsigned char* Wt = (unsigned char*)ws;  ws += (size_t)VOC * DIM;    // 65.5 MB
    unsigned char* Ht = (unsigned char*)ws;  ws += (size_t)N_TOK * DIM;  // 16.8 MB
    float* partMax = (float*)ws;             ws += (size_t)NVT * N_TOK * 4;
    float* partSum = (float*)ws;             ws += (size_t)NVT * N_TOK * 4;
    float* tgt     = (float*)ws;

    cast_zero_kernel<<<4096, 256, 0, stream>>>(H, W, Ht, Wt, out);
    lmhead_gemm<<<NNT * NVT, 256, 0, stream>>>(Ht, Wt, labels, partMax, partSum, tgt);
    reduce_kernel<<<N_TOK / 256, 256, 0, stream>>>(partMax, partSum, tgt, labels, out);
}